// Round 5
// baseline (301.720 us; speedup 1.0000x reference)
//
#include <hip/hip_runtime.h>

#define NQ   10000
#define BSZ  2
#define DIM  256
#define NH   8
#define HD   32
#define NLV  4
#define NPT  4
#define NV   13294           // 10000 + 2500 + 625 + 169
#define MT   (BSZ*NQ)        // 20000 rows
#define NOUT 384             // 256 offsets + 128 attn logits
#define NVAL (BSZ*NV*NH*HD)  // 6,806,528 f32 elements in value
#define GEMM_BLOCKS 939      // 3 x 313
#define PREP_BLOCKS 6647     // NVAL/4/256
#define QPB  16              // queries per sample block
#define SROW 130             // padded row stride for s_i/s_w (bank spread)

typedef float    floatx4 __attribute__((ext_vector_type(4)));
typedef int      intx4   __attribute__((ext_vector_type(4)));
typedef __bf16   bf16x8  __attribute__((ext_vector_type(8)));
typedef _Float16 halfx8  __attribute__((ext_vector_type(8)));
typedef _Float16 halfx4  __attribute__((ext_vector_type(4)));
typedef _Float16 halfx2  __attribute__((ext_vector_type(2)));

// pack two f32 -> two bf16 (round-half-up) in ONE v_perm_b32 + 2 adds
__device__ __forceinline__ unsigned pk_bf16(float lo, float hi) {
  return __builtin_amdgcn_perm(__float_as_uint(hi) + 0x8000u,
                               __float_as_uint(lo) + 0x8000u, 0x07060302);
}

__device__ __forceinline__ unsigned short f32_to_f16_bits(float f) {
  _Float16 h = (_Float16)f;
  return __builtin_bit_cast(unsigned short, h);
}

// ---------------- merged LDS-staged GEMM + value-cast ----------------
// bid < GEMM_BLOCKS: 64x128 MFMA tile of rawh(f16) = Q @ [W_off;W_attn]^T + bias.
// else: value f32 -> f16 cast.
__global__ __launch_bounds__(256) void gp_kernel(
    const float* __restrict__ query, const float* __restrict__ W_off,
    const float* __restrict__ W_attn,
    const float* __restrict__ b_off, const float* __restrict__ b_attn,
    const float* __restrict__ value,
    _Float16* __restrict__ rawh, _Float16* __restrict__ vf16) {
  const int bid = blockIdx.x;
  const int tid = threadIdx.x;
  if (bid >= GEMM_BLOCKS) {          // ---- value cast ----
    int i = (bid - GEMM_BLOCKS) * 256 + tid;
    if (i * 4 < NVAL) {
      floatx4 v = *(const floatx4*)&value[i * 4];
      halfx4 t = { (_Float16)v.x, (_Float16)v.y, (_Float16)v.z, (_Float16)v.w };
      *(uint2*)&vf16[i * 4] = *(const uint2*)&t;
    }
    return;
  }
  // ---- gemm part (n fastest: 3 consecutive blocks share A rows in L2) ----
  __shared__ unsigned short As[64][40];    // +8 pad
  __shared__ unsigned short Bs[128][40];
  const int n0 = (bid % 3) * 128;
  const int m0 = (bid / 3) * 64;
  const int wave = tid >> 6;
  const int lane = tid & 63;
  const int quad = lane >> 4;
  const int l16  = lane & 15;
  floatx4 acc[8] = {};
  const int ar = tid >> 2;        // 0..63
  const int ac = (tid & 3) * 8;   // 0,8,16,24
  const int br = tid >> 1;        // 0..127
  const int bc = (tid & 1) * 16;  // 0,16
  const float* __restrict__ Wsrc =
      (n0 < 256) ? (W_off + (size_t)n0 * DIM) : (W_attn + (size_t)(n0 - 256) * DIM);

  for (int k0 = 0; k0 < DIM; k0 += 32) {
    {
      int gm = m0 + ar;
      floatx4 a0 = {}, a1 = {};
      if (gm < MT) {
        const float* src = query + (size_t)gm * DIM + k0 + ac;
        a0 = *(const floatx4*)src;
        a1 = *(const floatx4*)(src + 4);
      }
      uint4 ua = { pk_bf16(a0.x, a0.y), pk_bf16(a0.z, a0.w),
                   pk_bf16(a1.x, a1.y), pk_bf16(a1.z, a1.w) };
      *(uint4*)&As[ar][ac] = ua;
    }
    {
      const float* src = Wsrc + (size_t)br * DIM + k0 + bc;
      floatx4 b0 = *(const floatx4*)src;
      floatx4 b1 = *(const floatx4*)(src + 4);
      floatx4 b2 = *(const floatx4*)(src + 8);
      floatx4 b3 = *(const floatx4*)(src + 12);
      uint4 u0 = { pk_bf16(b0.x, b0.y), pk_bf16(b0.z, b0.w),
                   pk_bf16(b1.x, b1.y), pk_bf16(b1.z, b1.w) };
      uint4 u1 = { pk_bf16(b2.x, b2.y), pk_bf16(b2.z, b2.w),
                   pk_bf16(b3.x, b3.y), pk_bf16(b3.z, b3.w) };
      *(uint4*)&Bs[br][bc]     = u0;
      *(uint4*)&Bs[br][bc + 8] = u1;
    }
    __syncthreads();
    bf16x8 a = *(const bf16x8*)&As[wave*16 + l16][quad*8];
    #pragma unroll
    for (int nt = 0; nt < 8; nt++) {
      bf16x8 b = *(const bf16x8*)&Bs[nt*16 + l16][quad*8];
      acc[nt] = __builtin_amdgcn_mfma_f32_16x16x32_bf16(a, b, acc[nt], 0, 0, 0);
    }
    __syncthreads();
  }
  // C/D layout: row = quad*4 + r, col = l16
  #pragma unroll
  for (int nt = 0; nt < 8; nt++) {
    int gn = n0 + nt*16 + l16;
    float bias = (gn < 256) ? b_off[gn] : b_attn[gn - 256];
    #pragma unroll
    for (int r = 0; r < 4; r++) {
      int gm = m0 + wave*16 + quad*4 + r;
      if (gm < MT) rawh[(size_t)gm*NOUT + gn] = (_Float16)(acc[nt][r] + bias);
    }
  }
}

// ---------------- softmax + bilinear sampling + fused output transpose ----------
// R15 = R14 + merged phase-4 passes. R14 counters: FETCH 49MB / WRITE 20.5MB
// (traffic fixed), occ 36.5%, VALU 46.5%, dur 52.6us -> no pipe saturated =>
// dependency-latency bound. The two serial query-passes each drained the
// gather pipeline (16 loads in flight). Merged loop: both rowb per pt, 8
// independent gathers/iter (~32 in flight), half the loop overhead.
union SampleSmem {
  struct { unsigned i[16 * SROW]; uint2 w[16 * SROW]; } s;  // 8,320 + 16,640 B
  float tr[16 * 260];                                       // 16,640 B
};

__global__ __launch_bounds__(256, 6) void sample_kernel(
    const _Float16* __restrict__ rawh, const _Float16* __restrict__ vf16,
    const float* __restrict__ refp, float* __restrict__ out) {
  // chunked-bijective XCD swizzle (nwg=1250, nxcd=8: q=156, r=2)
  const int orig = blockIdx.x;
  const int xcd  = orig & 7;
  const int rep  = orig >> 3;
  const int wg   = (xcd < 2 ? xcd * 157 : 2 * 157 + (xcd - 2) * 156) + rep;
  const int b  = wg / 625;
  const int q0 = (wg % 625) * QPB;
  const int mbase = b * NQ + q0;
  const int tid = threadIdx.x;

  __shared__ SampleSmem sm;

  constexpr int WLI[4] = {100, 50, 25, 13};
  constexpr int STI[4] = {0, 10000, 12500, 13125};

  const int p  = tid & 3;        // point within level
  const int r4 = tid >> 2;       // 0..63

  // ---- phases 1-3, twice: row = half*64 + r4 = ql*8 + h ----
  #pragma unroll
  for (int half = 0; half < 2; ++half) {
    const int row = half * 64 + r4;     // 0..127
    const int hh  = row & 7;
    const int ql0 = row >> 3;           // 0..15
    const int m   = mbase + ql0;
    const _Float16* rp = rawh + (size_t)m * NOUT;

    float lg[4], rpx[4], rpy[4];
    #pragma unroll
    for (int it = 0; it < 4; ++it) {
      unsigned oxy = *(const unsigned*)(rp + hh*32 + it*8 + p*2);  // (offx,offy) f16
      halfx2 o2 = __builtin_bit_cast(halfx2, oxy);
      lg[it] = (float)rp[256 + hh*16 + it*4 + p];
      float Wl = (float)WLI[it];
      float rx = refp[((size_t)m*NLV + it)*2 + 0];
      float ry = refp[((size_t)m*NLV + it)*2 + 1];
      // (ref + off/W)*2-1 -> pixel (align_corners=False): ref*W + off - 0.5
      rpx[it] = rx * Wl + (float)o2.x - 0.5f;
      rpy[it] = ry * Wl + (float)o2.y - 0.5f;
    }

    // register softmax over 16 logits per (ql,h); 4-lane group shares row
    float mx = fmaxf(fmaxf(lg[0], lg[1]), fmaxf(lg[2], lg[3]));
    mx = fmaxf(mx, __shfl_xor(mx, 1));
    mx = fmaxf(mx, __shfl_xor(mx, 2));
    float e[4], sden = 0.f;
    #pragma unroll
    for (int it = 0; it < 4; ++it) { e[it] = __expf(lg[it] - mx); sden += e[it]; }
    sden += __shfl_xor(sden, 1);
    sden += __shfl_xor(sden, 2);
    float inv = 1.f / sden;

    // clamped 2x2 patch base + remapped f16 weights
    #pragma unroll
    for (int it = 0; it < 4; ++it) {
      float aw = e[it] * inv;
      float px = rpx[it], py = rpy[it];
      float x0f = floorf(px), y0f = floorf(py);
      int x0 = (int)x0f, y0 = (int)y0f;
      float wx1 = px - x0f, wx0 = 1.f - wx1;
      float wy1 = py - y0f, wy0 = 1.f - wy1;
      const int Wl = WLI[it], STl = STI[it];
      // clamp patch base so all 4 taps stay inside this level
      int xb = min(max(x0, 0), Wl - 2);
      int yb = min(max(y0, 0), Wl - 2);
      // weight of clamped pixel xb+j = original weight of that pixel (0 if
      // that pixel was not an in-bounds tap of the original 2x2)
      float wxn0 = (xb == x0) ? wx0 : (xb == x0 + 1) ? wx1 : 0.f;
      float wxn1 = (xb == x0) ? wx1 : (xb == x0 - 1) ? wx0 : 0.f;
      float wyn0 = (yb == y0) ? wy0 : (yb == y0 + 1) ? wy1 : 0.f;
      float wyn1 = (yb == y0) ? wy1 : (yb == y0 - 1) ? wy0 : 0.f;
      unsigned idx0 = (unsigned)(STl + yb * Wl + xb);
      unsigned short w00 = f32_to_f16_bits(aw * wxn0 * wyn0);
      unsigned short w01 = f32_to_f16_bits(aw * wxn1 * wyn0);
      unsigned short w10 = f32_to_f16_bits(aw * wxn0 * wyn1);
      unsigned short w11 = f32_to_f16_bits(aw * wxn1 * wyn1);
      const int pt = it*4 + p;
      sm.s.i[pt*SROW + row] = idx0 | ((unsigned)Wl << 16);
      uint2 wp = { (unsigned)w00 | ((unsigned)w01 << 16),
                   (unsigned)w10 | ((unsigned)w11 << 16) };
      sm.s.w[pt*SROW + row] = wp;
    }
  }
  __syncthreads();

  // ---- phase 4: wave = 4 queries, BOTH handled per pt iteration ----
  const int wv = tid >> 6, lane = tid & 63;
  const int qh = lane >> 5;
  const int h  = (lane >> 2) & 7, cq = lane & 3;
  const char* vbh = (const char*)vf16 + (size_t)b * (NV*NH*HD*2) + h*64 + cq*16;
  const int ql_a  = wv*4 + qh;            // pass-0 query
  const int rowb0 = ql_a*8 + h;           // pass-1 row = rowb0 + 16
  floatx4 a00 = {0.f,0.f,0.f,0.f}, a01 = {0.f,0.f,0.f,0.f};
  floatx4 a10 = {0.f,0.f,0.f,0.f}, a11 = {0.f,0.f,0.f,0.f};
  #pragma unroll 2
  for (int pt = 0; pt < 16; ++pt) {
    unsigned iw0 = sm.s.i[pt*SROW + rowb0];
    unsigned iw1 = sm.s.i[pt*SROW + rowb0 + 16];
    uint2 wpA   = sm.s.w[pt*SROW + rowb0];
    uint2 wpB   = sm.s.w[pt*SROW + rowb0 + 16];
    halfx4 hwA = __builtin_bit_cast(halfx4, wpA);
    halfx4 hwB = __builtin_bit_cast(halfx4, wpB);
    int oA   = (int)(iw0 & 0xffffu) << 9;   // idx0*512 bytes
    int orA  = (int)(iw0 >> 16)     << 9;   // Wl*512 bytes
    int oB   = (int)(iw1 & 0xffffu) << 9;
    int orB  = (int)(iw1 >> 16)     << 9;
    const char* pA0 = vbh + oA;
    const char* pA2 = pA0 + orA;
    const char* pB0 = vbh + oB;
    const char* pB2 = pB0 + orB;
    halfx8 vA0 = *(const halfx8*)(pA0);        // (xb  , yb  )
    halfx8 vA1 = *(const halfx8*)(pA0 + 512);  // (xb+1, yb  )
    halfx8 vA2 = *(const halfx8*)(pA2);        // (xb  , yb+1)
    halfx8 vA3 = *(const halfx8*)(pA2 + 512);  // (xb+1, yb+1)
    halfx8 vB0 = *(const halfx8*)(pB0);
    halfx8 vB1 = *(const halfx8*)(pB0 + 512);
    halfx8 vB2 = *(const halfx8*)(pB2);
    halfx8 vB3 = *(const halfx8*)(pB2 + 512);
    #pragma unroll
    for (int t = 0; t < 4; ++t) {
      halfx8 v = (t==0) ? vA0 : (t==1) ? vA1 : (t==2) ? vA2 : vA3;
      _Float16 wt = hwA[t];
      // f16*f16 + f32 -> v_fma_mix_f32 (fused fpext, no v_cvt chain)
      a00.x += (float)wt * (float)v[0];
      a00.y += (float)wt * (float)v[1];
      a00.z += (float)wt * (float)v[2];
      a00.w += (float)wt * (float)v[3];
      a01.x += (float)wt * (float)v[4];
      a01.y += (float)wt * (float)v[5];
      a01.z += (float)wt * (float)v[6];
      a01.w += (float)wt * (float)v[7];
    }
    #pragma unroll
    for (int t = 0; t < 4; ++t) {
      halfx8 v = (t==0) ? vB0 : (t==1) ? vB1 : (t==2) ? vB2 : vB3;
      _Float16 wt = hwB[t];
      a10.x += (float)wt * (float)v[0];
      a10.y += (float)wt * (float)v[1];
      a10.z += (float)wt * (float)v[2];
      a10.w += (float)wt * (float)v[3];
      a11.x += (float)wt * (float)v[4];
      a11.y += (float)wt * (float)v[5];
      a11.z += (float)wt * (float)v[6];
      a11.w += (float)wt * (float)v[7];
    }
  }
  __syncthreads();   // all s.i/s.w reads done; reuse LDS for transpose staging

  // ---- phase 5: fused transpose. accs -> s_tr[q][ch] -> out[b,ch,q] ----
  {
    const int ch0 = h*32 + cq*8;
    *(floatx4*)&sm.tr[ql_a*260 + ch0]           = a00;
    *(floatx4*)&sm.tr[ql_a*260 + ch0 + 4]       = a01;
    *(floatx4*)&sm.tr[(ql_a + 2)*260 + ch0]     = a10;
    *(floatx4*)&sm.tr[(ql_a + 2)*260 + ch0 + 4] = a11;
  }
  __syncthreads();
  {
    const int ch = tid;                 // 0..255
    float vals[QPB];
    #pragma unroll
    for (int q = 0; q < QPB; ++q) vals[q] = sm.tr[q*260 + ch];
    float* op = out + ((size_t)b*DIM + ch)*NQ + q0;
    *(floatx4*)&op[0]  = *(const floatx4*)&vals[0];
    *(floatx4*)&op[4]  = *(const floatx4*)&vals[4];
    *(floatx4*)&op[8]  = *(const floatx4*)&vals[8];
    *(floatx4*)&op[12] = *(const floatx4*)&vals[12];
  }
}

extern "C" void kernel_launch(void* const* d_in, const int* in_sizes, int n_in,
                              void* d_out, int out_size, void* d_ws, size_t ws_size,
                              hipStream_t stream) {
  const float* query  = (const float*)d_in[0];
  const float* value  = (const float*)d_in[1];
  const float* refp   = (const float*)d_in[2];
  // d_in[3] = spatial_shapes (constants hardcoded)
  const float* W_off  = (const float*)d_in[4];
  const float* b_off  = (const float*)d_in[5];
  const float* W_attn = (const float*)d_in[6];
  const float* b_attn = (const float*)d_in[7];
  float* out = (float*)d_out;

  char* ws = (char*)d_ws;
  _Float16* rawh = (_Float16*)ws;                      // 15,360,000 B
  _Float16* vf16 = (_Float16*)(ws + 15360000);         // 13,613,056 B

  hipLaunchKernelGGL(gp_kernel, dim3(GEMM_BLOCKS + PREP_BLOCKS), dim3(256), 0, stream,
                     query, W_off, W_attn, b_off, b_attn, value, rawh, vf16);
  hipLaunchKernelGGL(sample_kernel, dim3(2 * (NQ / QPB)), dim3(256), 0, stream,
                     rawh, vf16, refp, out);
}

// Round 6
// 166.803 us; speedup vs baseline: 1.8088x; 1.8088x over previous
//
#include <hip/hip_runtime.h>

#define NQ   10000
#define BSZ  2
#define DIM  256
#define NH   8
#define HD   32
#define NLV  4
#define NPT  4
#define NV   13294           // 10000 + 2500 + 625 + 169
#define MT   (BSZ*NQ)        // 20000 rows
#define NOUT 384             // 256 offsets + 128 attn logits
#define NVAL (BSZ*NV*NH*HD)  // 6,806,528 f32 elements in value
#define GEMM_BLOCKS 939      // 3 x 313
#define PREP_BLOCKS 6647     // NVAL/4/256
#define QPB  16              // queries per sample block
#define SROW 130             // padded row stride for s_i/s_w (bank spread)

typedef float    floatx4 __attribute__((ext_vector_type(4)));
typedef int      intx4   __attribute__((ext_vector_type(4)));
typedef __bf16   bf16x8  __attribute__((ext_vector_type(8)));
typedef _Float16 halfx8  __attribute__((ext_vector_type(8)));
typedef _Float16 halfx4  __attribute__((ext_vector_type(4)));
typedef _Float16 halfx2  __attribute__((ext_vector_type(2)));

// pack two f32 -> two bf16 (round-half-up) in ONE v_perm_b32 + 2 adds
__device__ __forceinline__ unsigned pk_bf16(float lo, float hi) {
  return __builtin_amdgcn_perm(__float_as_uint(hi) + 0x8000u,
                               __float_as_uint(lo) + 0x8000u, 0x07060302);
}

__device__ __forceinline__ unsigned short f32_to_f16_bits(float f) {
  _Float16 h = (_Float16)f;
  return __builtin_bit_cast(unsigned short, h);
}

// ---------------- merged LDS-staged GEMM + value-cast ----------------
// bid < GEMM_BLOCKS: 64x128 MFMA tile of rawh(f16) = Q @ [W_off;W_attn]^T + bias.
// else: value f32 -> f16 cast.
__global__ __launch_bounds__(256) void gp_kernel(
    const float* __restrict__ query, const float* __restrict__ W_off,
    const float* __restrict__ W_attn,
    const float* __restrict__ b_off, const float* __restrict__ b_attn,
    const float* __restrict__ value,
    _Float16* __restrict__ rawh, _Float16* __restrict__ vf16) {
  const int bid = blockIdx.x;
  const int tid = threadIdx.x;
  if (bid >= GEMM_BLOCKS) {          // ---- value cast ----
    int i = (bid - GEMM_BLOCKS) * 256 + tid;
    if (i * 4 < NVAL) {
      floatx4 v = *(const floatx4*)&value[i * 4];
      halfx4 t = { (_Float16)v.x, (_Float16)v.y, (_Float16)v.z, (_Float16)v.w };
      *(uint2*)&vf16[i * 4] = *(const uint2*)&t;
    }
    return;
  }
  // ---- gemm part (n fastest: 3 consecutive blocks share A rows in L2) ----
  __shared__ unsigned short As[64][40];    // +8 pad
  __shared__ unsigned short Bs[128][40];
  const int n0 = (bid % 3) * 128;
  const int m0 = (bid / 3) * 64;
  const int wave = tid >> 6;
  const int lane = tid & 63;
  const int quad = lane >> 4;
  const int l16  = lane & 15;
  floatx4 acc[8] = {};
  const int ar = tid >> 2;        // 0..63
  const int ac = (tid & 3) * 8;   // 0,8,16,24
  const int br = tid >> 1;        // 0..127
  const int bc = (tid & 1) * 16;  // 0,16
  const float* __restrict__ Wsrc =
      (n0 < 256) ? (W_off + (size_t)n0 * DIM) : (W_attn + (size_t)(n0 - 256) * DIM);

  for (int k0 = 0; k0 < DIM; k0 += 32) {
    {
      int gm = m0 + ar;
      floatx4 a0 = {}, a1 = {};
      if (gm < MT) {
        const float* src = query + (size_t)gm * DIM + k0 + ac;
        a0 = *(const floatx4*)src;
        a1 = *(const floatx4*)(src + 4);
      }
      uint4 ua = { pk_bf16(a0.x, a0.y), pk_bf16(a0.z, a0.w),
                   pk_bf16(a1.x, a1.y), pk_bf16(a1.z, a1.w) };
      *(uint4*)&As[ar][ac] = ua;
    }
    {
      const float* src = Wsrc + (size_t)br * DIM + k0 + bc;
      floatx4 b0 = *(const floatx4*)src;
      floatx4 b1 = *(const floatx4*)(src + 4);
      floatx4 b2 = *(const floatx4*)(src + 8);
      floatx4 b3 = *(const floatx4*)(src + 12);
      uint4 u0 = { pk_bf16(b0.x, b0.y), pk_bf16(b0.z, b0.w),
                   pk_bf16(b1.x, b1.y), pk_bf16(b1.z, b1.w) };
      uint4 u1 = { pk_bf16(b2.x, b2.y), pk_bf16(b2.z, b2.w),
                   pk_bf16(b3.x, b3.y), pk_bf16(b3.z, b3.w) };
      *(uint4*)&Bs[br][bc]     = u0;
      *(uint4*)&Bs[br][bc + 8] = u1;
    }
    __syncthreads();
    bf16x8 a = *(const bf16x8*)&As[wave*16 + l16][quad*8];
    #pragma unroll
    for (int nt = 0; nt < 8; nt++) {
      bf16x8 b = *(const bf16x8*)&Bs[nt*16 + l16][quad*8];
      acc[nt] = __builtin_amdgcn_mfma_f32_16x16x32_bf16(a, b, acc[nt], 0, 0, 0);
    }
    __syncthreads();
  }
  // C/D layout: row = quad*4 + r, col = l16
  #pragma unroll
  for (int nt = 0; nt < 8; nt++) {
    int gn = n0 + nt*16 + l16;
    float bias = (gn < 256) ? b_off[gn] : b_attn[gn - 256];
    #pragma unroll
    for (int r = 0; r < 4; r++) {
      int gm = m0 + wave*16 + quad*4 + r;
      if (gm < MT) rawh[(size_t)gm*NOUT + gn] = (_Float16)(acc[nt][r] + bias);
    }
  }
}

// ---------------- softmax + bilinear sampling + fused output transpose ----------
// R16 = R15's merged phase-4 WITHOUT the VGPR ceiling that spilled it.
// R15 forensics: launch_bounds(256,6) caps alloc at ~85 VGPR; the unroll-2
// merged loop needs ~110 live -> allocator spilled loop state to scratch
// (WRITE 20.5->475MB, FETCH 49->319MB, VALUBusy 13%). Fix: plain
// launch_bounds(256) (alloc free, ~96-128 VGPR) + no unroll pragma (peak
// liveness = one pt: 8 in-flight gathers). LDS 25KB still sets residency
// (6 blocks/CU); VGPR at ~102 permits 5 waves/SIMD so occupancy unchanged.
union SampleSmem {
  struct { unsigned i[16 * SROW]; uint2 w[16 * SROW]; } s;  // 8,320 + 16,640 B
  float tr[16 * 260];                                       // 16,640 B
};

__global__ __launch_bounds__(256) void sample_kernel(
    const _Float16* __restrict__ rawh, const _Float16* __restrict__ vf16,
    const float* __restrict__ refp, float* __restrict__ out) {
  // chunked-bijective XCD swizzle (nwg=1250, nxcd=8: q=156, r=2)
  const int orig = blockIdx.x;
  const int xcd  = orig & 7;
  const int rep  = orig >> 3;
  const int wg   = (xcd < 2 ? xcd * 157 : 2 * 157 + (xcd - 2) * 156) + rep;
  const int b  = wg / 625;
  const int q0 = (wg % 625) * QPB;
  const int mbase = b * NQ + q0;
  const int tid = threadIdx.x;

  __shared__ SampleSmem sm;

  constexpr int WLI[4] = {100, 50, 25, 13};
  constexpr int STI[4] = {0, 10000, 12500, 13125};

  const int p  = tid & 3;        // point within level
  const int r4 = tid >> 2;       // 0..63

  // ---- phases 1-3, twice: row = half*64 + r4 = ql*8 + h ----
  #pragma unroll
  for (int half = 0; half < 2; ++half) {
    const int row = half * 64 + r4;     // 0..127
    const int hh  = row & 7;
    const int ql0 = row >> 3;           // 0..15
    const int m   = mbase + ql0;
    const _Float16* rp = rawh + (size_t)m * NOUT;

    float lg[4], rpx[4], rpy[4];
    #pragma unroll
    for (int it = 0; it < 4; ++it) {
      unsigned oxy = *(const unsigned*)(rp + hh*32 + it*8 + p*2);  // (offx,offy) f16
      halfx2 o2 = __builtin_bit_cast(halfx2, oxy);
      lg[it] = (float)rp[256 + hh*16 + it*4 + p];
      float Wl = (float)WLI[it];
      float rx = refp[((size_t)m*NLV + it)*2 + 0];
      float ry = refp[((size_t)m*NLV + it)*2 + 1];
      // (ref + off/W)*2-1 -> pixel (align_corners=False): ref*W + off - 0.5
      rpx[it] = rx * Wl + (float)o2.x - 0.5f;
      rpy[it] = ry * Wl + (float)o2.y - 0.5f;
    }

    // register softmax over 16 logits per (ql,h); 4-lane group shares row
    float mx = fmaxf(fmaxf(lg[0], lg[1]), fmaxf(lg[2], lg[3]));
    mx = fmaxf(mx, __shfl_xor(mx, 1));
    mx = fmaxf(mx, __shfl_xor(mx, 2));
    float e[4], sden = 0.f;
    #pragma unroll
    for (int it = 0; it < 4; ++it) { e[it] = __expf(lg[it] - mx); sden += e[it]; }
    sden += __shfl_xor(sden, 1);
    sden += __shfl_xor(sden, 2);
    float inv = 1.f / sden;

    // clamped 2x2 patch base + remapped f16 weights
    #pragma unroll
    for (int it = 0; it < 4; ++it) {
      float aw = e[it] * inv;
      float px = rpx[it], py = rpy[it];
      float x0f = floorf(px), y0f = floorf(py);
      int x0 = (int)x0f, y0 = (int)y0f;
      float wx1 = px - x0f, wx0 = 1.f - wx1;
      float wy1 = py - y0f, wy0 = 1.f - wy1;
      const int Wl = WLI[it], STl = STI[it];
      // clamp patch base so all 4 taps stay inside this level
      int xb = min(max(x0, 0), Wl - 2);
      int yb = min(max(y0, 0), Wl - 2);
      // weight of clamped pixel xb+j = original weight of that pixel (0 if
      // that pixel was not an in-bounds tap of the original 2x2)
      float wxn0 = (xb == x0) ? wx0 : (xb == x0 + 1) ? wx1 : 0.f;
      float wxn1 = (xb == x0) ? wx1 : (xb == x0 - 1) ? wx0 : 0.f;
      float wyn0 = (yb == y0) ? wy0 : (yb == y0 + 1) ? wy1 : 0.f;
      float wyn1 = (yb == y0) ? wy1 : (yb == y0 - 1) ? wy0 : 0.f;
      unsigned idx0 = (unsigned)(STl + yb * Wl + xb);
      unsigned short w00 = f32_to_f16_bits(aw * wxn0 * wyn0);
      unsigned short w01 = f32_to_f16_bits(aw * wxn1 * wyn0);
      unsigned short w10 = f32_to_f16_bits(aw * wxn0 * wyn1);
      unsigned short w11 = f32_to_f16_bits(aw * wxn1 * wyn1);
      const int pt = it*4 + p;
      sm.s.i[pt*SROW + row] = idx0 | ((unsigned)Wl << 16);
      uint2 wp = { (unsigned)w00 | ((unsigned)w01 << 16),
                   (unsigned)w10 | ((unsigned)w11 << 16) };
      sm.s.w[pt*SROW + row] = wp;
    }
  }
  __syncthreads();

  // ---- phase 4: wave = 4 queries, BOTH rows handled per pt iteration ----
  const int wv = tid >> 6, lane = tid & 63;
  const int qh = lane >> 5;
  const int h  = (lane >> 2) & 7, cq = lane & 3;
  const char* vbh = (const char*)vf16 + (size_t)b * (NV*NH*HD*2) + h*64 + cq*16;
  const int ql_a  = wv*4 + qh;            // pass-0 query
  const int rowb0 = ql_a*8 + h;           // pass-1 row = rowb0 + 16
  floatx4 a00 = {0.f,0.f,0.f,0.f}, a01 = {0.f,0.f,0.f,0.f};
  floatx4 a10 = {0.f,0.f,0.f,0.f}, a11 = {0.f,0.f,0.f,0.f};
  for (int pt = 0; pt < 16; ++pt) {
    unsigned iw0 = sm.s.i[pt*SROW + rowb0];
    unsigned iw1 = sm.s.i[pt*SROW + rowb0 + 16];
    uint2 wpA   = sm.s.w[pt*SROW + rowb0];
    uint2 wpB   = sm.s.w[pt*SROW + rowb0 + 16];
    halfx4 hwA = __builtin_bit_cast(halfx4, wpA);
    halfx4 hwB = __builtin_bit_cast(halfx4, wpB);
    int oA   = (int)(iw0 & 0xffffu) << 9;   // idx0*512 bytes
    int orA  = (int)(iw0 >> 16)     << 9;   // Wl*512 bytes
    int oB   = (int)(iw1 & 0xffffu) << 9;
    int orB  = (int)(iw1 >> 16)     << 9;
    const char* pA0 = vbh + oA;
    const char* pA2 = pA0 + orA;
    const char* pB0 = vbh + oB;
    const char* pB2 = pB0 + orB;
    halfx8 vA0 = *(const halfx8*)(pA0);        // (xb  , yb  )
    halfx8 vA1 = *(const halfx8*)(pA0 + 512);  // (xb+1, yb  )
    halfx8 vA2 = *(const halfx8*)(pA2);        // (xb  , yb+1)
    halfx8 vA3 = *(const halfx8*)(pA2 + 512);  // (xb+1, yb+1)
    halfx8 vB0 = *(const halfx8*)(pB0);
    halfx8 vB1 = *(const halfx8*)(pB0 + 512);
    halfx8 vB2 = *(const halfx8*)(pB2);
    halfx8 vB3 = *(const halfx8*)(pB2 + 512);
    #pragma unroll
    for (int t = 0; t < 4; ++t) {
      halfx8 v = (t==0) ? vA0 : (t==1) ? vA1 : (t==2) ? vA2 : vA3;
      _Float16 wt = hwA[t];
      // f16*f16 + f32 -> v_fma_mix_f32 (fused fpext, no v_cvt chain)
      a00.x += (float)wt * (float)v[0];
      a00.y += (float)wt * (float)v[1];
      a00.z += (float)wt * (float)v[2];
      a00.w += (float)wt * (float)v[3];
      a01.x += (float)wt * (float)v[4];
      a01.y += (float)wt * (float)v[5];
      a01.z += (float)wt * (float)v[6];
      a01.w += (float)wt * (float)v[7];
    }
    #pragma unroll
    for (int t = 0; t < 4; ++t) {
      halfx8 v = (t==0) ? vB0 : (t==1) ? vB1 : (t==2) ? vB2 : vB3;
      _Float16 wt = hwB[t];
      a10.x += (float)wt * (float)v[0];
      a10.y += (float)wt * (float)v[1];
      a10.z += (float)wt * (float)v[2];
      a10.w += (float)wt * (float)v[3];
      a11.x += (float)wt * (float)v[4];
      a11.y += (float)wt * (float)v[5];
      a11.z += (float)wt * (float)v[6];
      a11.w += (float)wt * (float)v[7];
    }
  }
  __syncthreads();   // all s.i/s.w reads done; reuse LDS for transpose staging

  // ---- phase 5: fused transpose. accs -> s_tr[q][ch] -> out[b,ch,q] ----
  {
    const int ch0 = h*32 + cq*8;
    *(floatx4*)&sm.tr[ql_a*260 + ch0]           = a00;
    *(floatx4*)&sm.tr[ql_a*260 + ch0 + 4]       = a01;
    *(floatx4*)&sm.tr[(ql_a + 2)*260 + ch0]     = a10;
    *(floatx4*)&sm.tr[(ql_a + 2)*260 + ch0 + 4] = a11;
  }
  __syncthreads();
  {
    const int ch = tid;                 // 0..255
    float vals[QPB];
    #pragma unroll
    for (int q = 0; q < QPB; ++q) vals[q] = sm.tr[q*260 + ch];
    float* op = out + ((size_t)b*DIM + ch)*NQ + q0;
    *(floatx4*)&op[0]  = *(const floatx4*)&vals[0];
    *(floatx4*)&op[4]  = *(const floatx4*)&vals[4];
    *(floatx4*)&op[8]  = *(const floatx4*)&vals[8];
    *(floatx4*)&op[12] = *(const floatx4*)&vals[12];
  }
}

extern "C" void kernel_launch(void* const* d_in, const int* in_sizes, int n_in,
                              void* d_out, int out_size, void* d_ws, size_t ws_size,
                              hipStream_t stream) {
  const float* query  = (const float*)d_in[0];
  const float* value  = (const float*)d_in[1];
  const float* refp   = (const float*)d_in[2];
  // d_in[3] = spatial_shapes (constants hardcoded)
  const float* W_off  = (const float*)d_in[4];
  const float* b_off  = (const float*)d_in[5];
  const float* W_attn = (const float*)d_in[6];
  const float* b_attn = (const float*)d_in[7];
  float* out = (float*)d_out;

  char* ws = (char*)d_ws;
  _Float16* rawh = (_Float16*)ws;                      // 15,360,000 B
  _Float16* vf16 = (_Float16*)(ws + 15360000);         // 13,613,056 B

  hipLaunchKernelGGL(gp_kernel, dim3(GEMM_BLOCKS + PREP_BLOCKS), dim3(256), 0, stream,
                     query, W_off, W_attn, b_off, b_attn, value, rawh, vf16);
  hipLaunchKernelGGL(sample_kernel, dim3(2 * (NQ / QPB)), dim3(256), 0, stream,
                     rawh, vf16, refp, out);
}

// Round 7
// 157.872 us; speedup vs baseline: 1.9112x; 1.0566x over previous
//
#include <hip/hip_runtime.h>

#define NQ   10000
#define BSZ  2
#define DIM  256
#define NH   8
#define HD   32
#define NLV  4
#define NPT  4
#define NV   13294           // 10000 + 2500 + 625 + 169
#define MT   (BSZ*NQ)        // 20000 rows
#define NOUT 384             // 256 offsets + 128 attn logits
#define NVAL (BSZ*NV*NH*HD)  // 6,806,528 f32 elements in value
#define GEMM_BLOCKS 939      // 3 x 313
#define PREP_BLOCKS 6647     // NVAL/4/256
#define QPB  8               // queries per sample block (R1 geometry)
#define SROW 66              // padded row stride (64 rows + 2)

typedef float    floatx4 __attribute__((ext_vector_type(4)));
typedef int      intx4   __attribute__((ext_vector_type(4)));
typedef __bf16   bf16x8  __attribute__((ext_vector_type(8)));
typedef _Float16 halfx8  __attribute__((ext_vector_type(8)));
typedef _Float16 halfx4  __attribute__((ext_vector_type(4)));
typedef _Float16 halfx2  __attribute__((ext_vector_type(2)));

// pack two f32 -> two bf16 (round-half-up) in ONE v_perm_b32 + 2 adds
__device__ __forceinline__ unsigned pk_bf16(float lo, float hi) {
  return __builtin_amdgcn_perm(__float_as_uint(hi) + 0x8000u,
                               __float_as_uint(lo) + 0x8000u, 0x07060302);
}

__device__ __forceinline__ unsigned short f32_to_f16_bits(float f) {
  _Float16 h = (_Float16)f;
  return __builtin_bit_cast(unsigned short, h);
}

// ---------------- merged LDS-staged GEMM + value-cast ----------------
// bid < GEMM_BLOCKS: 64x128 MFMA tile of rawh(f16) = Q @ [W_off;W_attn]^T + bias.
// else: value f32 -> f16 cast.
__global__ __launch_bounds__(256) void gp_kernel(
    const float* __restrict__ query, const float* __restrict__ W_off,
    const float* __restrict__ W_attn,
    const float* __restrict__ b_off, const float* __restrict__ b_attn,
    const float* __restrict__ value,
    _Float16* __restrict__ rawh, _Float16* __restrict__ vf16) {
  const int bid = blockIdx.x;
  const int tid = threadIdx.x;
  if (bid >= GEMM_BLOCKS) {          // ---- value cast ----
    int i = (bid - GEMM_BLOCKS) * 256 + tid;
    if (i * 4 < NVAL) {
      floatx4 v = *(const floatx4*)&value[i * 4];
      halfx4 t = { (_Float16)v.x, (_Float16)v.y, (_Float16)v.z, (_Float16)v.w };
      *(uint2*)&vf16[i * 4] = *(const uint2*)&t;
    }
    return;
  }
  // ---- gemm part (n fastest: 3 consecutive blocks share A rows in L2) ----
  __shared__ unsigned short As[64][40];    // +8 pad
  __shared__ unsigned short Bs[128][40];
  const int n0 = (bid % 3) * 128;
  const int m0 = (bid / 3) * 64;
  const int wave = tid >> 6;
  const int lane = tid & 63;
  const int quad = lane >> 4;
  const int l16  = lane & 15;
  floatx4 acc[8] = {};
  const int ar = tid >> 2;        // 0..63
  const int ac = (tid & 3) * 8;   // 0,8,16,24
  const int br = tid >> 1;        // 0..127
  const int bc = (tid & 1) * 16;  // 0,16
  const float* __restrict__ Wsrc =
      (n0 < 256) ? (W_off + (size_t)n0 * DIM) : (W_attn + (size_t)(n0 - 256) * DIM);

  for (int k0 = 0; k0 < DIM; k0 += 32) {
    {
      int gm = m0 + ar;
      floatx4 a0 = {}, a1 = {};
      if (gm < MT) {
        const float* src = query + (size_t)gm * DIM + k0 + ac;
        a0 = *(const floatx4*)src;
        a1 = *(const floatx4*)(src + 4);
      }
      uint4 ua = { pk_bf16(a0.x, a0.y), pk_bf16(a0.z, a0.w),
                   pk_bf16(a1.x, a1.y), pk_bf16(a1.z, a1.w) };
      *(uint4*)&As[ar][ac] = ua;
    }
    {
      const float* src = Wsrc + (size_t)br * DIM + k0 + bc;
      floatx4 b0 = *(const floatx4*)src;
      floatx4 b1 = *(const floatx4*)(src + 4);
      floatx4 b2 = *(const floatx4*)(src + 8);
      floatx4 b3 = *(const floatx4*)(src + 12);
      uint4 u0 = { pk_bf16(b0.x, b0.y), pk_bf16(b0.z, b0.w),
                   pk_bf16(b1.x, b1.y), pk_bf16(b1.z, b1.w) };
      uint4 u1 = { pk_bf16(b2.x, b2.y), pk_bf16(b2.z, b2.w),
                   pk_bf16(b3.x, b3.y), pk_bf16(b3.z, b3.w) };
      *(uint4*)&Bs[br][bc]     = u0;
      *(uint4*)&Bs[br][bc + 8] = u1;
    }
    __syncthreads();
    bf16x8 a = *(const bf16x8*)&As[wave*16 + l16][quad*8];
    #pragma unroll
    for (int nt = 0; nt < 8; nt++) {
      bf16x8 b = *(const bf16x8*)&Bs[nt*16 + l16][quad*8];
      acc[nt] = __builtin_amdgcn_mfma_f32_16x16x32_bf16(a, b, acc[nt], 0, 0, 0);
    }
    __syncthreads();
  }
  // C/D layout: row = quad*4 + r, col = l16
  #pragma unroll
  for (int nt = 0; nt < 8; nt++) {
    int gn = n0 + nt*16 + l16;
    float bias = (gn < 256) ? b_off[gn] : b_attn[gn - 256];
    #pragma unroll
    for (int r = 0; r < 4; r++) {
      int gm = m0 + wave*16 + quad*4 + r;
      if (gm < MT) rawh[(size_t)gm*NOUT + gn] = (_Float16)(acc[nt][r] + bias);
    }
  }
}

// ---------------- softmax + bilinear sampling + fused output transpose ----------
// R17: QPB back to 8 (R1's geometry). Cross-round data: sample time tracks
// resident waves (53%->47.5us, 36.5%->52.6, 27%->56.3); QPB=16's 1250-block
// grid caps blocks/CU at 4.9 (19.5 waves) regardless of LDS/VGPR. QPB=8 ->
// 2500 blocks -> 8 blocks/CU (wave-capped), ~32 waves/CU steady state; the
// 2500/2048 = 1.22-round tail is cheaper than halving peak occupancy.
// Kept from R14-16: u16 clamped-patch metadata (LDS 12,672 B), fused
// transpose + bijective XCD swizzle, v_fma_mix accumulate.
//  phase 1-3 (single pass, 64 rows x 4 lanes = 256 thr): coords+logits in
//    regs, 4-lane shfl_xor softmax, {base idx,Wl}+4 f16 w -> LDS
//  phase 4: lane = (qh,h,cq), ONE query per lane; 16 pts x (4 gathers + 32
//    v_fma_mix), unroll 2 (~8 loads in flight, ~52 VGPR, no cap -> no spill)
//  phase 5: accs -> tr[8][260] -> thread=ch writes 32 B to out[b,ch,q0..+7]
//    (4 consecutive blocks share each 128B out line; same XCD + adjacent in
//    time via swizzle -> L2 merges. WRITE_SIZE >30MB would falsify this.)
union SampleSmem {
  struct { unsigned i[16 * SROW]; uint2 w[16 * SROW]; } s;  // 4,224 + 8,448 B
  float tr[QPB * 260];                                      // 8,320 B
};

__global__ __launch_bounds__(256) void sample_kernel(
    const _Float16* __restrict__ rawh, const _Float16* __restrict__ vf16,
    const float* __restrict__ refp, float* __restrict__ out) {
  // chunked-bijective XCD swizzle (nwg=2500, nxcd=8: q=312, r=4)
  const int orig = blockIdx.x;
  const int xcd  = orig & 7;
  const int rep  = orig >> 3;
  const int wg   = (xcd < 4 ? xcd * 313 : 4 * 313 + (xcd - 4) * 312) + rep;
  const int b  = wg / 1250;
  const int q0 = (wg % 1250) * QPB;
  const int mbase = b * NQ + q0;
  const int tid = threadIdx.x;

  __shared__ SampleSmem sm;

  constexpr int WLI[4] = {100, 50, 25, 13};
  constexpr int STI[4] = {0, 10000, 12500, 13125};

  // ---- phase 1: thread (r=ql*8+h, p) owns 4 slots (one per level) ----
  const int p   = tid & 3;        // point within level
  const int r   = tid >> 2;       // 0..63 = ql*8 + h
  const int hh  = r & 7;
  const int ql0 = r >> 3;         // 0..7
  const int m   = mbase + ql0;
  const _Float16* rp = rawh + (size_t)m * NOUT;

  float lg[4], rpx[4], rpy[4];
  #pragma unroll
  for (int it = 0; it < 4; ++it) {
    unsigned oxy = *(const unsigned*)(rp + hh*32 + it*8 + p*2);  // (offx,offy) f16
    halfx2 o2 = __builtin_bit_cast(halfx2, oxy);
    lg[it] = (float)rp[256 + hh*16 + it*4 + p];
    float Wl = (float)WLI[it];
    float rx = refp[((size_t)m*NLV + it)*2 + 0];
    float ry = refp[((size_t)m*NLV + it)*2 + 1];
    // (ref + off/W)*2-1 -> pixel (align_corners=False): ref*W + off - 0.5
    rpx[it] = rx * Wl + (float)o2.x - 0.5f;
    rpy[it] = ry * Wl + (float)o2.y - 0.5f;
  }

  // ---- phase 2: register softmax over 16 logits per (ql,h) ----
  float mx = fmaxf(fmaxf(lg[0], lg[1]), fmaxf(lg[2], lg[3]));
  mx = fmaxf(mx, __shfl_xor(mx, 1));
  mx = fmaxf(mx, __shfl_xor(mx, 2));
  float e[4], sden = 0.f;
  #pragma unroll
  for (int it = 0; it < 4; ++it) { e[it] = __expf(lg[it] - mx); sden += e[it]; }
  sden += __shfl_xor(sden, 1);
  sden += __shfl_xor(sden, 2);
  float inv = 1.f / sden;

  // ---- phase 3: clamped 2x2 patch base + remapped f16 weights -> LDS ----
  #pragma unroll
  for (int it = 0; it < 4; ++it) {
    float aw = e[it] * inv;
    float px = rpx[it], py = rpy[it];
    float x0f = floorf(px), y0f = floorf(py);
    int x0 = (int)x0f, y0 = (int)y0f;
    float wx1 = px - x0f, wx0 = 1.f - wx1;
    float wy1 = py - y0f, wy0 = 1.f - wy1;
    const int Wl = WLI[it], STl = STI[it];
    // clamp patch base so all 4 taps stay inside this level
    int xb = min(max(x0, 0), Wl - 2);
    int yb = min(max(y0, 0), Wl - 2);
    // weight of clamped pixel xb+j = original weight of that pixel (0 if
    // that pixel was not an in-bounds tap of the original 2x2)
    float wxn0 = (xb == x0) ? wx0 : (xb == x0 + 1) ? wx1 : 0.f;
    float wxn1 = (xb == x0) ? wx1 : (xb == x0 - 1) ? wx0 : 0.f;
    float wyn0 = (yb == y0) ? wy0 : (yb == y0 + 1) ? wy1 : 0.f;
    float wyn1 = (yb == y0) ? wy1 : (yb == y0 - 1) ? wy0 : 0.f;
    unsigned idx0 = (unsigned)(STl + yb * Wl + xb);
    unsigned short w00 = f32_to_f16_bits(aw * wxn0 * wyn0);
    unsigned short w01 = f32_to_f16_bits(aw * wxn1 * wyn0);
    unsigned short w10 = f32_to_f16_bits(aw * wxn0 * wyn1);
    unsigned short w11 = f32_to_f16_bits(aw * wxn1 * wyn1);
    const int pt = it*4 + p;
    sm.s.i[pt*SROW + r] = idx0 | ((unsigned)Wl << 16);
    uint2 wp = { (unsigned)w00 | ((unsigned)w01 << 16),
                 (unsigned)w10 | ((unsigned)w11 << 16) };
    sm.s.w[pt*SROW + r] = wp;
  }
  __syncthreads();

  // ---- phase 4: lane = (qh, h, cq); ONE query per lane ----
  const int wv = tid >> 6, lane = tid & 63;
  const int qh = lane >> 5;
  const int h  = (lane >> 2) & 7, cq = lane & 3;
  const int ql = wv*2 + qh;               // 0..7
  const int rowb = ql*8 + h;              // 0..63
  const char* vbh = (const char*)vf16 + (size_t)b * (NV*NH*HD*2) + h*64 + cq*16;
  floatx4 acc0 = {0.f,0.f,0.f,0.f}, acc1 = {0.f,0.f,0.f,0.f};
  #pragma unroll 2
  for (int pt = 0; pt < 16; ++pt) {
    unsigned iw = sm.s.i[pt*SROW + rowb];
    uint2 wp   = sm.s.w[pt*SROW + rowb];
    halfx4 hw = __builtin_bit_cast(halfx4, wp);
    int o0   = (int)(iw & 0xffffu) << 9;   // idx0*512 bytes
    int orow = (int)(iw >> 16)     << 9;   // Wl*512 bytes
    const char* p0 = vbh + o0;
    const char* p2 = p0 + orow;
    halfx8 v0 = *(const halfx8*)(p0);        // (xb  , yb  )
    halfx8 v1 = *(const halfx8*)(p0 + 512);  // (xb+1, yb  )
    halfx8 v2 = *(const halfx8*)(p2);        // (xb  , yb+1)
    halfx8 v3 = *(const halfx8*)(p2 + 512);  // (xb+1, yb+1)
    #pragma unroll
    for (int t = 0; t < 4; ++t) {
      halfx8 v = (t==0) ? v0 : (t==1) ? v1 : (t==2) ? v2 : v3;
      _Float16 wt = hw[t];
      // f16*f16 + f32 -> v_fma_mix_f32 (fused fpext, no v_cvt chain)
      acc0.x += (float)wt * (float)v[0];
      acc0.y += (float)wt * (float)v[1];
      acc0.z += (float)wt * (float)v[2];
      acc0.w += (float)wt * (float)v[3];
      acc1.x += (float)wt * (float)v[4];
      acc1.y += (float)wt * (float)v[5];
      acc1.z += (float)wt * (float)v[6];
      acc1.w += (float)wt * (float)v[7];
    }
  }
  __syncthreads();   // all s.i/s.w reads done; reuse LDS for transpose staging

  // ---- phase 5: fused transpose. accs -> tr[q][ch] -> out[b,ch,q] ----
  {
    const int ch0 = h*32 + cq*8;
    *(floatx4*)&sm.tr[ql*260 + ch0]     = acc0;
    *(floatx4*)&sm.tr[ql*260 + ch0 + 4] = acc1;
  }
  __syncthreads();
  {
    const int ch = tid;                 // 0..255
    float vals[QPB];
    #pragma unroll
    for (int q = 0; q < QPB; ++q) vals[q] = sm.tr[q*260 + ch];
    float* op = out + ((size_t)b*DIM + ch)*NQ + q0;
    *(floatx4*)&op[0] = *(const floatx4*)&vals[0];
    *(floatx4*)&op[4] = *(const floatx4*)&vals[4];
  }
}

extern "C" void kernel_launch(void* const* d_in, const int* in_sizes, int n_in,
                              void* d_out, int out_size, void* d_ws, size_t ws_size,
                              hipStream_t stream) {
  const float* query  = (const float*)d_in[0];
  const float* value  = (const float*)d_in[1];
  const float* refp   = (const float*)d_in[2];
  // d_in[3] = spatial_shapes (constants hardcoded)
  const float* W_off  = (const float*)d_in[4];
  const float* b_off  = (const float*)d_in[5];
  const float* W_attn = (const float*)d_in[6];
  const float* b_attn = (const float*)d_in[7];
  float* out = (float*)d_out;

  char* ws = (char*)d_ws;
  _Float16* rawh = (_Float16*)ws;                      // 15,360,000 B
  _Float16* vf16 = (_Float16*)(ws + 15360000);         // 13,613,056 B

  hipLaunchKernelGGL(gp_kernel, dim3(GEMM_BLOCKS + PREP_BLOCKS), dim3(256), 0, stream,
                     query, W_off, W_attn, b_off, b_attn, value, rawh, vf16);
  hipLaunchKernelGGL(sample_kernel, dim3(BSZ * (NQ / QPB)), dim3(256), 0, stream,
                     rawh, vf16, refp, out);
}